// Round 1
// baseline (232.351 us; speedup 1.0000x reference)
//
#include <hip/hip_runtime.h>

// TemporalPSPGate: state_t = ALPHA*state_{t-1} + x_t ; out_t = x_t * sigmoid(state_t)
// x: (T,B,H,N,D) = (16,16,8,256,64) fp32. Recurrence is element-wise over the
// 2,097,152 spatial slots; T axis carried in a register per thread.
// Memory-bound: 128 MiB in + 128 MiB out => ~43 us floor at 6.3 TB/s.

#define T_STEPS 16
#define SPATIAL (16LL * 8LL * 256LL * 64LL)   // B*H*N*D = 2,097,152
#define ALPHA_F 0.60653065971263342f          // exp(-1/2)

__global__ __launch_bounds__(256) void
TemporalPSPGate_35613868819159_kernel(const float* __restrict__ x,
                                      float* __restrict__ out) {
    // 4 elements per thread, float4 vectorized. Grid covers SPATIAL/4 threads.
    const long long i = (((long long)blockIdx.x * blockDim.x) + threadIdx.x) * 4LL;
    if (i >= SPATIAL) return;

    float4 state = make_float4(0.f, 0.f, 0.f, 0.f);

    #pragma unroll
    for (int t = 0; t < T_STEPS; ++t) {
        const long long off = (long long)t * SPATIAL + i;
        const float4 xv = *reinterpret_cast<const float4*>(x + off);

        state.x = ALPHA_F * state.x + xv.x;
        state.y = ALPHA_F * state.y + xv.y;
        state.z = ALPHA_F * state.z + xv.z;
        state.w = ALPHA_F * state.w + xv.w;

        float4 o;
        o.x = xv.x * (1.0f / (1.0f + __expf(-state.x)));
        o.y = xv.y * (1.0f / (1.0f + __expf(-state.y)));
        o.z = xv.z * (1.0f / (1.0f + __expf(-state.z)));
        o.w = xv.w * (1.0f / (1.0f + __expf(-state.w)));

        *reinterpret_cast<float4*>(out + off) = o;
    }
}

extern "C" void kernel_launch(void* const* d_in, const int* in_sizes, int n_in,
                              void* d_out, int out_size, void* d_ws, size_t ws_size,
                              hipStream_t stream) {
    const float* x = (const float*)d_in[0];
    float* out = (float*)d_out;

    const long long n_threads = SPATIAL / 4;          // 524,288
    const int block = 256;
    const int grid = (int)((n_threads + block - 1) / block);  // 2048

    TemporalPSPGate_35613868819159_kernel<<<grid, block, 0, stream>>>(x, out);
}

// Round 2
// 230.717 us; speedup vs baseline: 1.0071x; 1.0071x over previous
//
#include <hip/hip_runtime.h>

// TemporalPSPGate: state_t = ALPHA*state_{t-1} + x_t ; out_t = x_t * sigmoid(state_t)
// x: (T,B,H,N,D) = (16,16,8,256,64) fp32.
// R1 post-mortem: VGPR=28 showed compiler serialized load->use per t
// (16 exposed latencies/wave, 2.4 TB/s, 83us). Fix: explicit 16-deep
// register prefetch so all loads are in flight before the compute chain.

#define T_STEPS 16
#define SPATIAL (16LL * 8LL * 256LL * 64LL)   // B*H*N*D = 2,097,152
#define VEC4    (SPATIAL / 4)                 // 524,288 float4 slots per t
#define ALPHA_F 0.60653065971263342f          // exp(-1/2)

__global__ __launch_bounds__(256) void
TemporalPSPGate_35613868819159_kernel(const float4* __restrict__ x,
                                      float4* __restrict__ out) {
    const int i = blockIdx.x * 256 + threadIdx.x;   // float4 index, [0, VEC4)

    // Phase 1: issue all 16 loads back-to-back (16 KB in flight per wave).
    float4 xv[T_STEPS];
    #pragma unroll
    for (int t = 0; t < T_STEPS; ++t) {
        xv[t] = x[(long long)t * VEC4 + i];
    }

    // Phase 2: recurrence + gate + store. The state chain is 4-cycle FMA
    // deps; sigmoids/stores are off-chain and pipeline freely.
    float4 st = make_float4(0.f, 0.f, 0.f, 0.f);
    #pragma unroll
    for (int t = 0; t < T_STEPS; ++t) {
        st.x = ALPHA_F * st.x + xv[t].x;
        st.y = ALPHA_F * st.y + xv[t].y;
        st.z = ALPHA_F * st.z + xv[t].z;
        st.w = ALPHA_F * st.w + xv[t].w;

        float4 o;
        o.x = xv[t].x * (1.0f / (1.0f + __expf(-st.x)));
        o.y = xv[t].y * (1.0f / (1.0f + __expf(-st.y)));
        o.z = xv[t].z * (1.0f / (1.0f + __expf(-st.z)));
        o.w = xv[t].w * (1.0f / (1.0f + __expf(-st.w)));

        out[(long long)t * VEC4 + i] = o;
    }
}

extern "C" void kernel_launch(void* const* d_in, const int* in_sizes, int n_in,
                              void* d_out, int out_size, void* d_ws, size_t ws_size,
                              hipStream_t stream) {
    const float4* x = (const float4*)d_in[0];
    float4* out = (float4*)d_out;

    const int block = 256;
    const int grid = (int)(VEC4 / block);   // 2048

    TemporalPSPGate_35613868819159_kernel<<<grid, block, 0, stream>>>(x, out);
}